// Round 10
// baseline (727.217 us; speedup 1.0000x reference)
//
#include <hip/hip_runtime.h>

typedef __attribute__((ext_vector_type(8))) short sh8;       // 8 bf16 (4 VGPRs)
typedef __attribute__((ext_vector_type(4))) float f32x4;

#define E_EDGES 100000
#define E_PAD   100096   // 391 * 256
#define N_NODES 20000

#define BAR() do { __builtin_amdgcn_sched_barrier(0); __builtin_amdgcn_s_barrier(); __builtin_amdgcn_sched_barrier(0); } while (0)

__device__ __forceinline__ unsigned short f2bf(float f) {
  union { float f; unsigned int u; } v; v.f = f;
  unsigned int r = v.u + 0x7FFFu + ((v.u >> 16) & 1u);   // RNE
  return (unsigned short)(r >> 16);
}

__device__ __forceinline__ void async16(const void* g, void* l) {
  __builtin_amdgcn_global_load_lds((const __attribute__((address_space(1))) unsigned int*)g,
                                   (__attribute__((address_space(3))) unsigned int*)l,
                                   16, 0, 0);
}

// ---- w2 (f32 [1024][1024] k-major) -> w2t (bf16 [n][k]) ----
__global__ void transpose_w2_kernel(const float* __restrict__ w2, unsigned short* __restrict__ w2t) {
  __shared__ float tile[32][33];
  int b = blockIdx.x;
  int bx = b & 31, by = b >> 5;
  int lx = threadIdx.x & 31, ly = threadIdx.x >> 5;
#pragma unroll
  for (int j = 0; j < 4; ++j)
    tile[ly + j*8][lx] = w2[(size_t)(by*32 + ly + j*8)*1024 + bx*32 + lx];
  __syncthreads();
#pragma unroll
  for (int j = 0; j < 4; ++j)
    w2t[(size_t)(bx*32 + ly + j*8)*1024 + by*32 + lx] = f2bf(tile[lx][ly + j*8]);
}

// ---- h1 = relu(ea @ w1 + b1) -> bf16 [E_PAD][1024]; 16 edges per block ----
__global__ __launch_bounds__(256)
void edge_mlp1_kernel(const float* __restrict__ ea, const float* __restrict__ w1,
                      const float* __restrict__ b1, unsigned short* __restrict__ h1) {
  __shared__ float eas[16][16];
  const int tid = threadIdx.x;
  const int e0 = blockIdx.x * 16;
  {
    int g = tid >> 4, d = tid & 15;
    int ge = e0 + g;
    eas[g][d] = (ge < E_EDGES) ? ea[(size_t)ge*16 + d] : 0.f;
  }
  __syncthreads();
  const int c0 = tid * 4;
  float4 bb = *(const float4*)(b1 + c0);
  float4 acc[16];
#pragma unroll
  for (int g = 0; g < 16; ++g) acc[g] = bb;
#pragma unroll
  for (int d = 0; d < 16; ++d) {
    float4 w = *(const float4*)(w1 + (size_t)d*1024 + c0);
#pragma unroll
    for (int g = 0; g < 16; ++g) {
      float ev = eas[g][d];
      acc[g].x += ev*w.x; acc[g].y += ev*w.y; acc[g].z += ev*w.z; acc[g].w += ev*w.w;
    }
  }
#pragma unroll
  for (int g = 0; g < 16; ++g) {
    ushort4 o;
    if (e0 + g < E_EDGES) {
      o.x = f2bf(fmaxf(acc[g].x, 0.f)); o.y = f2bf(fmaxf(acc[g].y, 0.f));
      o.z = f2bf(fmaxf(acc[g].z, 0.f)); o.w = f2bf(fmaxf(acc[g].w, 0.f));
    } else {
      o.x = o.y = o.z = o.w = 0;
    }
    *(ushort4*)(h1 + (size_t)(e0 + g)*1024 + c0) = o;
  }
}

// ---- cnt[dst] += 1 ----
__global__ void count_kernel(const int* __restrict__ dst, float* __restrict__ cnt) {
  int t = blockIdx.x*256 + threadIdx.x;
  if (t < E_EDGES) atomicAdd(&cnt[dst[t]], 1.0f);
}

// ==== 256x256x(BK=64) bf16 MFMA GEMM: A triple-buffered (2 ahead), B double-
// buffered (1 ahead), counted vmcnt(4) (never drains in main loop), one
// barrier per K-tile, both-sides XOR swizzle, fused msg contraction+scatter.
// R5 schedule with the spill confounder removed: launch_bounds(512,1)
// (VGPR cap 512, ~200 used) + per-kk fragment loads. 1 block/CU, 2 waves/SIMD.
__global__ __launch_bounds__(512, 1)
void gemm_scatter_kernel(const unsigned short* __restrict__ h1,
                         const unsigned short* __restrict__ w2t,
                         const float* __restrict__ b2,
                         const float* __restrict__ xin,
                         const int* __restrict__ src,
                         const int* __restrict__ dst,
                         float* __restrict__ agg) {
  // 160 KB exact: A bufs @0,32K,64K; B bufs @96K,128K
  __shared__ __align__(16) unsigned char lds[163840];
  float* msgA = (float*)lds;                               // [256][33] = 33792 B
  float* msgB = (float*)(lds + 33792);                     // [256][33]
  float (*xg)[8] = (float (*)[8])(lds + 67584);            // 8 KB
  int* dsts = (int*)(lds + 75776);                         // 1 KB

  const int tid  = threadIdx.x;
  const int wave = tid >> 6, lane = tid & 63;
  const int wm = wave >> 2, wn = wave & 3;                 // 2 x 4 waves, 128x64 each
  const int lr = lane >> 4, lc = lane & 15;

  // bijective XCD swizzle: nwg = 1564 = 8*195 + 4
  const int bid = blockIdx.x;
  const int xcd = bid & 7, idx = bid >> 3;
  const int logical = (xcd < 4 ? xcd*196 : 784 + (xcd - 4)*195) + idx;
  const int tile_m = logical >> 2, tile_n = logical & 3;
  const long e0 = (long)tile_m * 256, n0 = (long)tile_n * 256;

  const unsigned short* Ag = h1  + (size_t)e0*1024;
  const unsigned short* Bg = w2t + (size_t)n0*1024;

  const int l8   = lane >> 3;
  const int scol = 8*((lane & 7) ^ l8);                    // pre-swizzled source col
  const int srow = wave*8 + l8;                            // + 64*j
  const int swzb = (lc & 7) << 4;                          // read-side byte XOR

#define ABUF(i) (lds + (i)*32768)
#define BBUF(i) (lds + 98304 + (i)*32768)
#define STAGE_A(bi, kt) do { _Pragma("unroll")                                      \
    for (int j = 0; j < 4; ++j)                                                     \
      async16(Ag + (size_t)(srow + 64*j)*1024 + (kt)*64 + scol,                     \
              ABUF(bi) + (wave*8 + 64*j)*128); } while (0)
#define STAGE_B(bi, kt) do { _Pragma("unroll")                                      \
    for (int j = 0; j < 4; ++j)                                                     \
      async16(Bg + (size_t)(srow + 64*j)*1024 + (kt)*64 + scol,                     \
              BBUF(bi) + (wave*8 + 64*j)*128); } while (0)

  f32x4 acc[8][4];
#pragma unroll
  for (int m = 0; m < 8; ++m)
#pragma unroll
    for (int n = 0; n < 4; ++n) acc[m][n] = (f32x4){0.f, 0.f, 0.f, 0.f};

  // prologue: oldest 8 = {B0, A0}; newest 4 = A1 (may stay in flight at kt=0)
  STAGE_B(0, 0);
  STAGE_A(0, 0);
  STAGE_A(1, 1);

#pragma unroll
  for (int kt = 0; kt < 16; ++kt) {
    if (kt == 15) asm volatile("s_waitcnt vmcnt(0)" ::: "memory");
    else          asm volatile("s_waitcnt vmcnt(4)" ::: "memory");
    BAR();                                   // tile kt resident; buf(kt-1) reads done
    if (kt + 1 < 16) STAGE_B((kt + 1) & 1, kt + 1);   // 1 ahead (L2-resident)
    if (kt + 2 < 16) STAGE_A((kt + 2) % 3, kt + 2);   // 2 ahead (covers HBM latency)
    const char* Ab = (const char*)ABUF(kt % 3);
    const char* Bb = (const char*)BBUF(kt & 1);
#pragma unroll
    for (int kk = 0; kk < 2; ++kk) {
      sh8 a[8], b[4];
#pragma unroll
      for (int n = 0; n < 4; ++n)
        b[n] = *(const sh8*)(Bb + (wn*64 + n*16 + lc)*128 + ((kk*64 + lr*16) ^ swzb));
#pragma unroll
      for (int m = 0; m < 8; ++m)
        a[m] = *(const sh8*)(Ab + (wm*128 + m*16 + lc)*128 + ((kk*64 + lr*16) ^ swzb));
      __builtin_amdgcn_s_setprio(1);
#pragma unroll
      for (int m = 0; m < 8; ++m)
#pragma unroll
        for (int n = 0; n < 4; ++n)
          acc[m][n] = __builtin_amdgcn_mfma_f32_16x16x32_bf16(a[m], b[n], acc[m][n], 0, 0, 0);
      __builtin_amdgcn_s_setprio(0);
    }
  }
#undef STAGE_A
#undef STAGE_B
#undef ABUF
#undef BBUF

  // ---- epilogue (staging LDS dead; vmcnt drained at kt=15) ----
  __syncthreads();
  {
    int e = tid >> 1, half = tid & 1;
    long ge = e0 + e;
    float4 v = make_float4(0.f, 0.f, 0.f, 0.f);
    if (ge < E_EDGES) v = *(const float4*)(xin + (size_t)src[ge]*32 + tile_n*8 + half*4);
    *(float4*)&xg[e][half*4] = v;
    if (tid < 256) dsts[tid] = (e0 + tid < E_EDGES) ? dst[e0 + tid] : -1;
  }
  float b2c[4];
#pragma unroll
  for (int n = 0; n < 4; ++n) b2c[n] = b2[n0 + wn*64 + n*16 + lc];
  __syncthreads();

  // wave covers di = {2wn, 2wn+1}; o = lc (n even) / lc+16 (n odd)
  if ((wn & 1) == 0) {
    float* mb = (wn == 0) ? msgA : msgB;
#pragma unroll
    for (int m = 0; m < 8; ++m)
#pragma unroll
      for (int r = 0; r < 4; ++r) {
        int e = wm*128 + m*16 + lr*4 + r;
        float x0 = xg[e][2*wn], x1 = xg[e][2*wn + 1];
        mb[e*33 + lc]      = (acc[m][0][r] + b2c[0])*x0 + (acc[m][2][r] + b2c[2])*x1;
        mb[e*33 + lc + 16] = (acc[m][1][r] + b2c[1])*x0 + (acc[m][3][r] + b2c[3])*x1;
      }
  }
  __syncthreads();
  if ((wn & 1) == 1) {
    float* mb = (wn == 1) ? msgA : msgB;
#pragma unroll
    for (int m = 0; m < 8; ++m)
#pragma unroll
      for (int r = 0; r < 4; ++r) {
        int e = wm*128 + m*16 + lr*4 + r;
        float x0 = xg[e][2*wn], x1 = xg[e][2*wn + 1];
        mb[e*33 + lc]      += (acc[m][0][r] + b2c[0])*x0 + (acc[m][2][r] + b2c[2])*x1;
        mb[e*33 + lc + 16] += (acc[m][1][r] + b2c[1])*x0 + (acc[m][3][r] + b2c[3])*x1;
      }
  }
  __syncthreads();
  for (int t = tid; t < 256*32; t += 512) {
    int e = t >> 5, o = t & 31;
    int dn = dsts[e];
    if (dn >= 0) atomicAdd(&agg[(size_t)dn*32 + o], msgA[e*33 + o] + msgB[e*33 + o]);
  }
}

// ---- node update: out = relu(agg/max(cnt,1) + x@root + bias) ----
__global__ void node_update_kernel(const float* __restrict__ agg, const float* __restrict__ cnt,
                                   const float* __restrict__ xin, const float* __restrict__ root,
                                   const float* __restrict__ bias, float* __restrict__ outp) {
  int t = blockIdx.x*256 + threadIdx.x;
  if (t >= N_NODES*32) return;
  int n = t >> 5, i = t & 31;
  const float* xr = xin + (size_t)n*32;
  float s = bias[i];
#pragma unroll
  for (int j = 0; j < 32; ++j) s += xr[j]*root[j*32 + i];
  float c = cnt[n]; c = c > 1.f ? c : 1.f;
  float v = agg[t]/c + s;
  outp[t] = fmaxf(v, 0.f);
}

// ---- final: out = h @ lin_w + lin_b ----
__global__ void final_linear_kernel(const float* __restrict__ h, const float* __restrict__ lw,
                                    const float* __restrict__ lb, float* __restrict__ out) {
  int t = blockIdx.x*256 + threadIdx.x;
  if (t >= N_NODES*10) return;
  int n = t / 10, k = t % 10;
  const float* hr = h + (size_t)n*32;
  float s = lb[k];
#pragma unroll
  for (int i = 0; i < 32; ++i) s += hr[i]*lw[i*10 + k];
  out[t] = s;
}

extern "C" void kernel_launch(void* const* d_in, const int* in_sizes, int n_in,
                              void* d_out, int out_size, void* d_ws, size_t ws_size,
                              hipStream_t stream) {
  const float* x     = (const float*)d_in[0];
  const int*   ei    = (const int*)d_in[1];
  const float* ea    = (const float*)d_in[2];
  const float* e1w1  = (const float*)d_in[3];
  const float* e1b1  = (const float*)d_in[4];
  const float* e1w2  = (const float*)d_in[5];
  const float* e1b2  = (const float*)d_in[6];
  const float* root1 = (const float*)d_in[7];
  const float* bias1 = (const float*)d_in[8];
  const float* e2w1  = (const float*)d_in[9];
  const float* e2b1  = (const float*)d_in[10];
  const float* e2w2  = (const float*)d_in[11];
  const float* e2b2  = (const float*)d_in[12];
  const float* root2 = (const float*)d_in[13];
  const float* bias2 = (const float*)d_in[14];
  const float* linw  = (const float*)d_in[15];
  const float* linb  = (const float*)d_in[16];
  const int* srcp = ei;
  const int* dstp = ei + E_EDGES;

  char* ws = (char*)d_ws;
  size_t off = 0;
  auto alloc = [&](size_t bytes) { void* p = ws + off; off += (bytes + 255) & ~(size_t)255; return p; };
  unsigned short* h1buf = (unsigned short*)alloc((size_t)E_PAD*1024*2);   // 205 MB
  unsigned short* w2t   = (unsigned short*)alloc((size_t)1024*1024*2);
  float* agg  = (float*)alloc((size_t)N_NODES*32*4);
  float* cnt  = (float*)alloc((size_t)N_NODES*4);
  float* out1 = (float*)alloc((size_t)N_NODES*32*4);
  float* hbuf = (float*)alloc((size_t)N_NODES*32*4);
  (void)ws_size; (void)n_in; (void)in_sizes; (void)out_size;

  hipMemsetAsync(agg, 0, (size_t)N_NODES*32*4, stream);
  hipMemsetAsync(cnt, 0, (size_t)N_NODES*4, stream);
  count_kernel<<<(E_EDGES + 255)/256, 256, 0, stream>>>(dstp, cnt);

  const int gemm_grid = (E_PAD/256) * 4;   // 391 * 4 = 1564

  // ---- layer 1 ----
  transpose_w2_kernel<<<1024, 256, 0, stream>>>(e1w2, w2t);
  edge_mlp1_kernel<<<E_PAD/16, 256, 0, stream>>>(ea, e1w1, e1b1, h1buf);
  gemm_scatter_kernel<<<gemm_grid, 512, 0, stream>>>(h1buf, w2t, e1b2, x, srcp, dstp, agg);
  node_update_kernel<<<(N_NODES*32 + 255)/256, 256, 0, stream>>>(agg, cnt, x, root1, bias1, out1);

  // ---- layer 2 ----
  hipMemsetAsync(agg, 0, (size_t)N_NODES*32*4, stream);
  transpose_w2_kernel<<<1024, 256, 0, stream>>>(e2w2, w2t);
  edge_mlp1_kernel<<<E_PAD/16, 256, 0, stream>>>(ea, e2w1, e2b1, h1buf);
  gemm_scatter_kernel<<<gemm_grid, 512, 0, stream>>>(h1buf, w2t, e2b2, out1, srcp, dstp, agg);
  node_update_kernel<<<(N_NODES*32 + 255)/256, 256, 0, stream>>>(agg, cnt, out1, root2, bias2, hbuf);

  final_linear_kernel<<<(N_NODES*10 + 255)/256, 256, 0, stream>>>(hbuf, linw, linb, (float*)d_out);
}